// Round 7
// baseline (520.380 us; speedup 1.0000x reference)
//
#include <hip/hip_runtime.h>
#include <math.h>

// ---------------------------------------------------------------------------
// Problem constants (B=8, N1=128, N2=256, D=128, L=3, NH=54)
// Packed row space: rows 0..1023 = ligand (b*128+i), rows 1024..3071 = target
// (1024 + b*256 + j).
// ---------------------------------------------------------------------------
#define BB 8
#define N1C 128
#define N2C 256
#define DC 128
#define NHC 54
#define ROWS_L 1024
#define ROWS_T 2048
#define ROWS_ALL 3072

// ---------------------------------------------------------------------------
// Reductions (wave64)
// ---------------------------------------------------------------------------
__device__ __forceinline__ float wredSum(float v) {
#pragma unroll
  for (int o = 32; o > 0; o >>= 1) v += __shfl_down(v, o);
  return v;
}
__device__ float blockSum(float v) {
  __shared__ float red[9];
  v = wredSum(v);
  int lane = threadIdx.x & 63, wid = threadIdx.x >> 6;
  __syncthreads();
  if (lane == 0) red[wid] = v;
  __syncthreads();
  if (threadIdx.x == 0) {
    float s = 0.f;
    int nw = (blockDim.x + 63) >> 6;
    for (int i = 0; i < nw; ++i) s += red[i];
    red[8] = s;
  }
  __syncthreads();
  return red[8];
}

// ---------------------------------------------------------------------------
// k_prep: merged adj12 + embedding + GAT-weight-fuse + GRU-weight-transpose.
// grid = 1024 + 384 + 99 + 1152 = 2659 blocks, 256 threads.
// ---------------------------------------------------------------------------
__global__ __launch_bounds__(256) void k_prep(
    const float* __restrict__ LP, const float* __restrict__ TP,
    float* __restrict__ AD, const float* __restrict__ LH,
    const float* __restrict__ TH, const float* __restrict__ EW,
    float* __restrict__ H0, const float* __restrict__ GWp,
    const float* __restrict__ GBp, const float* __restrict__ ATT,
    float* __restrict__ WA, float* __restrict__ bA,
    const float* __restrict__ IH, const float* __restrict__ HH,
    float* __restrict__ GIHT, float* __restrict__ GHHT) {
  int bid = blockIdx.x, tid = threadIdx.x;
  if (bid < 1024) {  // ---- adj12 ----
    long idx = (long)bid * 256 + tid;
    int j = idx & (N2C - 1);
    long t = idx >> 8;
    int i = (int)(t & (N1C - 1));
    int b = (int)(t >> 7);
    float dx = LP[((long)b * N1C + i) * 3 + 0] - TP[((long)b * N2C + j) * 3 + 0];
    float dy = LP[((long)b * N1C + i) * 3 + 1] - TP[((long)b * N2C + j) * 3 + 1];
    float dz = LP[((long)b * N1C + i) * 3 + 2] - TP[((long)b * N2C + j) * 3 + 2];
    float d = sqrtf(dx * dx + dy * dy + dz * dz + 1e-10f);
    if (d < 0.5f) d = 1e10f;
    AD[idx] = (d <= 5.0f && d > 1e-3f) ? 1.f : 0.f;
  } else if (bid < 1024 + 384) {  // ---- embedding, 8 rows/block ----
    int r0 = (bid - 1024) * 8;
    __shared__ float xs[8][NHC];
    for (int t = tid; t < 8 * NHC; t += 256) {
      int rr = r0 + t / NHC, c = t % NHC;
      xs[t / NHC][c] = (rr < ROWS_L) ? LH[(long)rr * NHC + c]
                                     : TH[(long)(rr - ROWS_L) * NHC + c];
    }
    __syncthreads();
    int d = tid & 127, rb = (tid >> 7) * 4;
    float a[4] = {0.f, 0.f, 0.f, 0.f};
#pragma unroll 6
    for (int k = 0; k < NHC; ++k) {
      float wv = EW[(long)k * DC + d];
#pragma unroll
      for (int r = 0; r < 4; ++r) a[r] += xs[rb + r][k] * wv;
    }
#pragma unroll
    for (int r = 0; r < 4; ++r) H0[(long)(r0 + rb + r) * DC + d] = a[r];
  } else if (bid < 1024 + 384 + 99) {  // ---- wfuse: WA_l = W_l @ ATT_l ----
    int q = bid - 1408;
    int l = q / 33, bx = q % 33;
    const float* Wl = GWp + (long)l * DC * DC;
    const float* Al = ATT + (long)l * DC * DC;
    if (bx == 32) {
      if (tid < 128) {
        float acc = 0.f;
#pragma unroll 8
        for (int m = 0; m < DC; ++m)
          acc += GBp[l * DC + m] * Al[(long)m * DC + tid];
        bA[l * DC + tid] = acc;
      }
    } else {
      __shared__ float xs2[4][DC];
      int r0 = bx * 4;
      for (int t = tid; t < 4 * DC; t += 256)
        xs2[t >> 7][t & 127] = Wl[(long)r0 * DC + t];
      __syncthreads();
      if (tid < 128) {
        int d = tid;
        float a0 = 0.f, a1 = 0.f, a2 = 0.f, a3 = 0.f;
#pragma unroll 8
        for (int m = 0; m < DC; ++m) {
          float av = Al[(long)m * DC + d];
          a0 += xs2[0][m] * av;
          a1 += xs2[1][m] * av;
          a2 += xs2[2][m] * av;
          a3 += xs2[3][m] * av;
        }
        float* out = WA + (long)l * DC * DC + (long)r0 * DC + d;
        out[0] = a0;
        out[DC] = a1;
        out[2 * DC] = a2;
        out[3 * DC] = a3;
      }
    }
  } else {  // ---- GRU weight transposes ----
    long idx = (long)(bid - 1507) * 256 + tid;
    if (idx < 6L * 49152) {
      int a = (int)(idx / 49152);
      int rem = (int)(idx % 49152);
      int l = a >> 1, whh = a & 1;
      int c = rem / 384, rr = rem % 384;
      const float* src = (whh ? HH : IH) + (long)l * 49152;
      float* dst = (whh ? GHHT : GIHT) + (long)l * 49152;
      dst[(long)c * 384 + rr] = src[(long)rr * 128 + c];
    }
  }
}

// ---------------------------------------------------------------------------
// Dual-weight GEMM: Y1 = A@B1+b1, Y2 = A@B2+b2.  A [3072][128], B k-major
// [128][128].  64x64 tile, 256 thr, 4x4/thread.  grid (48, 4): by>>1 = head,
// (by&1)*64 = col tile.
// ---------------------------------------------------------------------------
__global__ __launch_bounds__(256) void k_gemm2w(
    const float* __restrict__ A, const float* __restrict__ B1,
    const float* __restrict__ b1, const float* __restrict__ B2,
    const float* __restrict__ b2, float* __restrict__ Y1,
    float* __restrict__ Y2) {
  int r0 = blockIdx.x * 64;
  int head = blockIdx.y >> 1;
  int c0 = (blockIdx.y & 1) * 64;
  const float* B = head ? B2 : B1;
  const float* bp = head ? b2 : b1;
  float* Y = head ? Y2 : Y1;
  __shared__ float as_t[32][68], bs[32][68];
  int tid = threadIdx.x, tx = tid & 15, ty = tid >> 4;
  float acc[4][4];
#pragma unroll
  for (int r = 0; r < 4; ++r)
#pragma unroll
    for (int c = 0; c < 4; ++c) acc[r][c] = 0.f;
  for (int kc = 0; kc < DC; kc += 32) {
    __syncthreads();
    for (int t = tid; t < 2048; t += 256) {
      int kk = t & 31, rr = t >> 5;
      as_t[kk][rr] = A[(long)(r0 + rr) * DC + kc + kk];
    }
    for (int t = tid; t < 2048; t += 256) {
      int cc = t & 63, kk = t >> 6;
      bs[kk][cc] = B[(long)(kc + kk) * DC + c0 + cc];
    }
    __syncthreads();
#pragma unroll
    for (int kk = 0; kk < 32; ++kk) {
      float4 a = *(const float4*)&as_t[kk][ty * 4];
      float4 bv = *(const float4*)&bs[kk][tx * 4];
      acc[0][0] = fmaf(a.x, bv.x, acc[0][0]);
      acc[0][1] = fmaf(a.x, bv.y, acc[0][1]);
      acc[0][2] = fmaf(a.x, bv.z, acc[0][2]);
      acc[0][3] = fmaf(a.x, bv.w, acc[0][3]);
      acc[1][0] = fmaf(a.y, bv.x, acc[1][0]);
      acc[1][1] = fmaf(a.y, bv.y, acc[1][1]);
      acc[1][2] = fmaf(a.y, bv.z, acc[1][2]);
      acc[1][3] = fmaf(a.y, bv.w, acc[1][3]);
      acc[2][0] = fmaf(a.z, bv.x, acc[2][0]);
      acc[2][1] = fmaf(a.z, bv.y, acc[2][1]);
      acc[2][2] = fmaf(a.z, bv.z, acc[2][2]);
      acc[2][3] = fmaf(a.z, bv.w, acc[2][3]);
      acc[3][0] = fmaf(a.w, bv.x, acc[3][0]);
      acc[3][1] = fmaf(a.w, bv.y, acc[3][1]);
      acc[3][2] = fmaf(a.w, bv.z, acc[3][2]);
      acc[3][3] = fmaf(a.w, bv.w, acc[3][3]);
    }
  }
  float bvv[4];
#pragma unroll
  for (int c = 0; c < 4; ++c) bvv[c] = bp ? bp[c0 + tx * 4 + c] : 0.f;
#pragma unroll
  for (int r = 0; r < 4; ++r) {
    float4 o;
    o.x = acc[r][0] + bvv[0];
    o.y = acc[r][1] + bvv[1];
    o.z = acc[r][2] + bvv[2];
    o.w = acc[r][3] + bvv[3];
    *(float4*)&Y[(long)(r0 + ty * 4 + r) * DC + c0 + tx * 4] = o;
  }
}

// ---------------------------------------------------------------------------
// k_gemmS: S = E1 @ NT^T per batch/graph (ea = S + S^T done in smagg2).
// 64x64 tiles; grid = 32 (ligand) + 128 (target) = 160 blocks.
// ---------------------------------------------------------------------------
__global__ __launch_bounds__(256) void k_gemmS(const float* __restrict__ E1p,
                                               const float* __restrict__ NTp,
                                               float* __restrict__ SL,
                                               float* __restrict__ ST) {
  int id = blockIdx.x;
  int Nn, base, j0, k0;
  float* Sout;
  if (id < 32) {
    int b = id >> 2;
    Nn = N1C;
    base = b * N1C;
    j0 = ((id >> 1) & 1) * 64;
    k0 = (id & 1) * 64;
    Sout = SL + (long)b * N1C * N1C;
  } else {
    int q = id - 32;
    int b = q >> 4;
    Nn = N2C;
    base = ROWS_L + b * N2C;
    j0 = ((q >> 2) & 3) * 64;
    k0 = (q & 3) * 64;
    Sout = ST + (long)b * N2C * N2C;
  }
  __shared__ float as_t[32][68], bs_t[32][68];
  int tid = threadIdx.x, tx = tid & 15, ty = tid >> 4;
  float acc[4][4];
#pragma unroll
  for (int r = 0; r < 4; ++r)
#pragma unroll
    for (int c = 0; c < 4; ++c) acc[r][c] = 0.f;
  for (int kc = 0; kc < DC; kc += 32) {
    __syncthreads();
    for (int t = tid; t < 2048; t += 256) {
      int kk = t & 31, rr = t >> 5;
      as_t[kk][rr] = E1p[(long)(base + j0 + rr) * DC + kc + kk];
      bs_t[kk][rr] = NTp[(long)(base + k0 + rr) * DC + kc + kk];
    }
    __syncthreads();
#pragma unroll
    for (int kk = 0; kk < 32; ++kk) {
      float4 a = *(const float4*)&as_t[kk][ty * 4];
      float4 bv = *(const float4*)&bs_t[kk][tx * 4];
      acc[0][0] = fmaf(a.x, bv.x, acc[0][0]);
      acc[0][1] = fmaf(a.x, bv.y, acc[0][1]);
      acc[0][2] = fmaf(a.x, bv.z, acc[0][2]);
      acc[0][3] = fmaf(a.x, bv.w, acc[0][3]);
      acc[1][0] = fmaf(a.y, bv.x, acc[1][0]);
      acc[1][1] = fmaf(a.y, bv.y, acc[1][1]);
      acc[1][2] = fmaf(a.y, bv.z, acc[1][2]);
      acc[1][3] = fmaf(a.y, bv.w, acc[1][3]);
      acc[2][0] = fmaf(a.z, bv.x, acc[2][0]);
      acc[2][1] = fmaf(a.z, bv.y, acc[2][1]);
      acc[2][2] = fmaf(a.z, bv.z, acc[2][2]);
      acc[2][3] = fmaf(a.z, bv.w, acc[2][3]);
      acc[3][0] = fmaf(a.w, bv.x, acc[3][0]);
      acc[3][1] = fmaf(a.w, bv.y, acc[3][1]);
      acc[3][2] = fmaf(a.w, bv.z, acc[3][2]);
      acc[3][3] = fmaf(a.w, bv.w, acc[3][3]);
    }
  }
#pragma unroll
  for (int r = 0; r < 4; ++r) {
    float4 o;
    o.x = acc[r][0];
    o.y = acc[r][1];
    o.z = acc[r][2];
    o.w = acc[r][3];
    *(float4*)&Sout[(long)(j0 + ty * 4 + r) * Nn + k0 + tx * 4] = o;
  }
}

// ---------------------------------------------------------------------------
// k_smagg2: load ea = (S + S^T) masked -> row softmax -> OUT = relu(P@NT)
// -> gated residual.  16 rows/block, 256 thr (32 dgrp x 4 rowgrp x 2 khalf).
// grid (16, 8, 2): z=0 ligand (x<8), z=1 target.
// ---------------------------------------------------------------------------
__global__ __launch_bounds__(256) void k_smagg2(
    const float* __restrict__ SL, const float* __restrict__ ST,
    const float* __restrict__ ADJL, const float* __restrict__ ADJT,
    const float* __restrict__ NTp, const float* __restrict__ Xp,
    const float* __restrict__ GW, const float* __restrict__ GB,
    float* __restrict__ Y) {
  int z = blockIdx.z;
  int N = z ? N2C : N1C;
  if (blockIdx.x * 16 >= N) return;
  int baseRow = z ? ROWS_L : 0;
  const float* S = z ? ST : SL;
  const float* ADJ = z ? ADJT : ADJL;
  int b = blockIdx.y, i0 = blockIdx.x * 16;
  __shared__ float ps[16][N2C + 4];
  __shared__ float col[32][DC + 4];
  __shared__ float red[16];
  int tid = threadIdx.x;
  const float* Sb = S + (long)b * N * N;
  const float* Ab = ADJ + (long)b * N * N;
  int ls = z ? 8 : 7;
  for (int t = tid; t < 16 * N; t += 256) {
    int r = t >> ls, k = t & (N - 1);
    float ad = Ab[(long)(i0 + r) * N + k];
    float v = (ad > 1e-6f)
                  ? Sb[(long)(i0 + r) * N + k] + Sb[(long)k * N + i0 + r]
                  : -9e15f;
    ps[r][k] = v;
  }
  __syncthreads();
  {  // softmax, 16 lanes/row
    int r = tid >> 4, l = tid & 15;
    float m = -INFINITY;
    for (int k = l; k < N; k += 16) m = fmaxf(m, ps[r][k]);
#pragma unroll
    for (int o = 8; o > 0; o >>= 1) m = fmaxf(m, __shfl_xor(m, o));
    float s = 0.f;
    for (int k = l; k < N; k += 16) {
      float p = expf(ps[r][k] - m);
      ps[r][k] = p;
      s += p;
    }
#pragma unroll
    for (int o = 8; o > 0; o >>= 1) s += __shfl_xor(s, o);
    float inv = 1.f / s;
    for (int k = l; k < N; k += 16) ps[r][k] *= inv;
  }
  // aggregate
  int dgrp = tid & 31, rowgrp = (tid >> 5) & 3, khalf = tid >> 7;
  int d0 = dgrp * 4;
  float acc[4][4];
#pragma unroll
  for (int r = 0; r < 4; ++r)
#pragma unroll
    for (int c = 0; c < 4; ++c) acc[r][c] = 0.f;
  const float* NTb = NTp + (long)(baseRow + b * N) * DC;
  for (int kc = 0; kc < N; kc += 32) {
    __syncthreads();
    for (int t = tid; t < 32 * DC; t += 256)
      col[t >> 7][t & 127] = NTb[(long)(kc + (t >> 7)) * DC + (t & 127)];
    __syncthreads();
    int kb = khalf * 16;
#pragma unroll
    for (int k4 = 0; k4 < 16; k4 += 4) {
      float4 c0v = *(const float4*)&col[kb + k4 + 0][d0];
      float4 c1v = *(const float4*)&col[kb + k4 + 1][d0];
      float4 c2v = *(const float4*)&col[kb + k4 + 2][d0];
      float4 c3v = *(const float4*)&col[kb + k4 + 3][d0];
#pragma unroll
      for (int rr = 0; rr < 4; ++rr) {
        float4 p = *(const float4*)&ps[rowgrp * 4 + rr][kc + kb + k4];
        acc[rr][0] = fmaf(p.x, c0v.x, acc[rr][0]);
        acc[rr][1] = fmaf(p.x, c0v.y, acc[rr][1]);
        acc[rr][2] = fmaf(p.x, c0v.z, acc[rr][2]);
        acc[rr][3] = fmaf(p.x, c0v.w, acc[rr][3]);
        acc[rr][0] = fmaf(p.y, c1v.x, acc[rr][0]);
        acc[rr][1] = fmaf(p.y, c1v.y, acc[rr][1]);
        acc[rr][2] = fmaf(p.y, c1v.z, acc[rr][2]);
        acc[rr][3] = fmaf(p.y, c1v.w, acc[rr][3]);
        acc[rr][0] = fmaf(p.z, c2v.x, acc[rr][0]);
        acc[rr][1] = fmaf(p.z, c2v.y, acc[rr][1]);
        acc[rr][2] = fmaf(p.z, c2v.z, acc[rr][2]);
        acc[rr][3] = fmaf(p.z, c2v.w, acc[rr][3]);
        acc[rr][0] = fmaf(p.w, c3v.x, acc[rr][0]);
        acc[rr][1] = fmaf(p.w, c3v.y, acc[rr][1]);
        acc[rr][2] = fmaf(p.w, c3v.z, acc[rr][2]);
        acc[rr][3] = fmaf(p.w, c3v.w, acc[rr][3]);
      }
    }
  }
  // khalf reduction through LDS (reuse col)
  __syncthreads();
  float* xch = &col[0][0];
  if (khalf == 1) {
    float* dst = xch + (tid & 127) * 16;
#pragma unroll
    for (int rr = 0; rr < 4; ++rr)
#pragma unroll
      for (int dd = 0; dd < 4; ++dd) dst[rr * 4 + dd] = acc[rr][dd];
  }
  __syncthreads();
  float xv[4][4], ov[4][4];
  if (khalf == 0) {
    const float* src = xch + tid * 16;
    float part[4] = {0.f, 0.f, 0.f, 0.f};
    float gwd[4], gwo[4];
#pragma unroll
    for (int dd = 0; dd < 4; ++dd) {
      gwd[dd] = GW[d0 + dd];
      gwo[dd] = GW[DC + d0 + dd];
    }
#pragma unroll
    for (int rr = 0; rr < 4; ++rr) {
      int row = rowgrp * 4 + rr;
      float4 x4 = *(const float4*)&Xp[(long)(baseRow + b * N + i0 + row) * DC + d0];
      xv[rr][0] = x4.x;
      xv[rr][1] = x4.y;
      xv[rr][2] = x4.z;
      xv[rr][3] = x4.w;
#pragma unroll
      for (int dd = 0; dd < 4; ++dd) {
        float o = fmaxf(acc[rr][dd] + src[rr * 4 + dd], 0.f);
        ov[rr][dd] = o;
        part[rr] += xv[rr][dd] * gwd[dd] + o * gwo[dd];
      }
    }
#pragma unroll
    for (int off = 16; off > 0; off >>= 1)
#pragma unroll
      for (int rr = 0; rr < 4; ++rr) part[rr] += __shfl_xor(part[rr], off);
    if (dgrp == 0)
#pragma unroll
      for (int rr = 0; rr < 4; ++rr) red[rowgrp * 4 + rr] = part[rr];
  }
  __syncthreads();
  if (khalf == 0) {
    float gb = GB[0];
#pragma unroll
    for (int rr = 0; rr < 4; ++rr) {
      int row = rowgrp * 4 + rr;
      float g = 1.f / (1.f + expf(-(red[row] + gb)));
      float4 y;
      y.x = g * xv[rr][0] + (1.f - g) * ov[rr][0];
      y.y = g * xv[rr][1] + (1.f - g) * ov[rr][1];
      y.z = g * xv[rr][2] + (1.f - g) * ov[rr][2];
      y.w = g * xv[rr][3] + (1.f - g) * ov[rr][3];
      *(float4*)&Y[(long)(baseRow + b * N + i0 + row) * DC + d0] = y;
    }
  }
}

// ---------------------------------------------------------------------------
// k_msg2v: msg = relu(t1 + max_j m2_j * ev_ij).  8 rows/block, 256 thr
// (32 dgrp x 8 rows).  grid (32, 8, 2): z=0 ligand (x<16), z=1 target.
// ---------------------------------------------------------------------------
__global__ __launch_bounds__(256) void k_msg2v(const float* __restrict__ T1,
                                               const float* __restrict__ M2,
                                               const float* __restrict__ EV,
                                               float* __restrict__ MSG) {
  int z = blockIdx.z, b = blockIdx.y;
  int Ni = z ? N2C : N1C, Nj = z ? N1C : N2C;
  if (blockIdx.x * 8 >= Ni) return;
  int t1off = z ? ROWS_L : 0, m2off = z ? 0 : ROWS_L;
  long ev_is = z ? 1L : (long)N2C, ev_js = z ? (long)N2C : 1L;
  int i0 = blockIdx.x * 8;
  __shared__ float m2s[32][DC + 4];
  __shared__ float evs[8][36];
  int dgrp = threadIdx.x & 31, row = threadIdx.x >> 5;
  int d0 = dgrp * 4;
  float a0 = -INFINITY, a1 = -INFINITY, a2 = -INFINITY, a3 = -INFINITY;
  const float* M2b = M2 + (long)(m2off + b * Nj) * DC;
  const float* EVb = EV + (long)b * (N1C * N2C);
  for (int j0 = 0; j0 < Nj; j0 += 32) {
    __syncthreads();
    for (int t = threadIdx.x; t < 32 * DC; t += 256)
      m2s[t >> 7][t & 127] = M2b[(long)(j0 + (t >> 7)) * DC + (t & 127)];
    for (int t = threadIdx.x; t < 256; t += 256)
      evs[t >> 5][t & 31] =
          EVb[(long)(i0 + (t >> 5)) * ev_is + (long)(j0 + (t & 31)) * ev_js];
    __syncthreads();
#pragma unroll 8
    for (int jj = 0; jj < 32; ++jj) {
      float4 m4 = *(const float4*)&m2s[jj][d0];
      float e = evs[row][jj];
      a0 = fmaxf(a0, m4.x * e);
      a1 = fmaxf(a1, m4.y * e);
      a2 = fmaxf(a2, m4.z * e);
      a3 = fmaxf(a3, m4.w * e);
    }
  }
  long grow = t1off + (long)b * Ni + i0 + row;
  float4 t4 = *(const float4*)&T1[grow * DC + d0];
  float4 o;
  o.x = fmaxf(t4.x + a0, 0.f);
  o.y = fmaxf(t4.y + a1, 0.f);
  o.z = fmaxf(t4.z + a2, 0.f);
  o.w = fmaxf(t4.w + a3, 0.f);
  *(float4*)&MSG[grow * DC + d0] = o;
}

// ---------------------------------------------------------------------------
// k_ggru: GI = MSG@WihT+bih, GH = H@WhhT+bhh as 128x128-tile GEMMs,
// 8x8/thread.  grid (24, 6): by<3 -> gi col-tile, else gh.
// ---------------------------------------------------------------------------
__global__ __launch_bounds__(256) void k_ggru(
    const float* __restrict__ MSGp, const float* __restrict__ Hp,
    const float* __restrict__ WihT, const float* __restrict__ WhhT,
    const float* __restrict__ bih, const float* __restrict__ bhh,
    float* __restrict__ GI, float* __restrict__ GH) {
  int r0 = blockIdx.x * 128;
  int by = blockIdx.y;
  bool hh = by >= 3;
  int c0 = (hh ? by - 3 : by) * 128;
  const float* A = hh ? Hp : MSGp;
  const float* B = hh ? WhhT : WihT;
  const float* bp = hh ? bhh : bih;
  float* Y = hh ? GH : GI;
  __shared__ float as_t[32][132], bs[32][132];
  int tid = threadIdx.x, tx = tid & 15, ty = tid >> 4;
  float acc[8][8];
#pragma unroll
  for (int r = 0; r < 8; ++r)
#pragma unroll
    for (int c = 0; c < 8; ++c) acc[r][c] = 0.f;
  for (int kc = 0; kc < DC; kc += 32) {
    __syncthreads();
    for (int t = tid; t < 4096; t += 256) {
      int kk = t & 31, rr = t >> 5;
      as_t[kk][rr] = A[(long)(r0 + rr) * DC + kc + kk];
    }
    for (int t = tid; t < 4096; t += 256) {
      int cc = t & 127, kk = t >> 7;
      bs[kk][cc] = B[(long)(kc + kk) * 384 + c0 + cc];
    }
    __syncthreads();
#pragma unroll
    for (int kk = 0; kk < 32; ++kk) {
      float4 A0 = *(const float4*)&as_t[kk][ty * 8];
      float4 A1 = *(const float4*)&as_t[kk][ty * 8 + 4];
      float4 B0 = *(const float4*)&bs[kk][tx * 8];
      float4 B1 = *(const float4*)&bs[kk][tx * 8 + 4];
      float av[8] = {A0.x, A0.y, A0.z, A0.w, A1.x, A1.y, A1.z, A1.w};
      float bw[8] = {B0.x, B0.y, B0.z, B0.w, B1.x, B1.y, B1.z, B1.w};
#pragma unroll
      for (int r = 0; r < 8; ++r)
#pragma unroll
        for (int c = 0; c < 8; ++c) acc[r][c] = fmaf(av[r], bw[c], acc[r][c]);
    }
  }
  float bvv[8];
#pragma unroll
  for (int c = 0; c < 8; ++c) bvv[c] = bp[c0 + tx * 8 + c];
#pragma unroll
  for (int r = 0; r < 8; ++r) {
    float4 o0, o1;
    o0.x = acc[r][0] + bvv[0];
    o0.y = acc[r][1] + bvv[1];
    o0.z = acc[r][2] + bvv[2];
    o0.w = acc[r][3] + bvv[3];
    o1.x = acc[r][4] + bvv[4];
    o1.y = acc[r][5] + bvv[5];
    o1.z = acc[r][6] + bvv[6];
    o1.w = acc[r][7] + bvv[7];
    long rowi = (long)(r0 + ty * 8 + r) * 384 + c0 + tx * 8;
    *(float4*)&Y[rowi] = o0;
    *(float4*)&Y[rowi + 4] = o1;
  }
}

// GRU elementwise combine (vectorized).  grid 384 x 256.
__global__ __launch_bounds__(256) void k_comb(const float* __restrict__ GI,
                                              const float* __restrict__ GH,
                                              const float* __restrict__ Hp,
                                              float* __restrict__ Y) {
  int idx = blockIdx.x * 256 + threadIdx.x;
  int r = idx >> 5;
  int d4 = (idx & 31) * 4;
  long gbase = (long)r * 384 + d4;
  float4 ir = *(const float4*)&GI[gbase];
  float4 iz = *(const float4*)&GI[gbase + 128];
  float4 in4 = *(const float4*)&GI[gbase + 256];
  float4 hr = *(const float4*)&GH[gbase];
  float4 hz = *(const float4*)&GH[gbase + 128];
  float4 hn = *(const float4*)&GH[gbase + 256];
  float4 h4 = *(const float4*)&Hp[(long)r * DC + d4];
  float4 y;
  {
    float rg = 1.f / (1.f + expf(-(ir.x + hr.x)));
    float zg = 1.f / (1.f + expf(-(iz.x + hz.x)));
    float ng = tanhf(in4.x + rg * hn.x);
    y.x = (1.f - zg) * ng + zg * h4.x;
  }
  {
    float rg = 1.f / (1.f + expf(-(ir.y + hr.y)));
    float zg = 1.f / (1.f + expf(-(iz.y + hz.y)));
    float ng = tanhf(in4.y + rg * hn.y);
    y.y = (1.f - zg) * ng + zg * h4.y;
  }
  {
    float rg = 1.f / (1.f + expf(-(ir.z + hr.z)));
    float zg = 1.f / (1.f + expf(-(iz.z + hz.z)));
    float ng = tanhf(in4.z + rg * hn.z);
    y.z = (1.f - zg) * ng + zg * h4.z;
  }
  {
    float rg = 1.f / (1.f + expf(-(ir.w + hr.w)));
    float zg = 1.f / (1.f + expf(-(iz.w + hz.w)));
    float ng = tanhf(in4.w + rg * hn.w);
    y.w = (1.f - zg) * ng + zg * h4.w;
  }
  *(float4*)&Y[(long)r * DC + d4] = y;
}

// ---------------------------------------------------------------------------
// k_featg: pairwise feature heads.  Ligand rows -> U (normal layout, +bias);
// target rows -> V transposed [b][d][j].  Head A / head B by blockIdx.y>>1.
// grid (48, 4).
// ---------------------------------------------------------------------------
__global__ __launch_bounds__(256) void k_featg(
    const float* __restrict__ X, const float* __restrict__ Aw1,
    const float* __restrict__ Ab1, const float* __restrict__ Bw1,
    const float* __restrict__ Bb1, float* __restrict__ UA,
    float* __restrict__ UB, float* __restrict__ VAT, float* __restrict__ VBT) {
  int r0 = blockIdx.x * 64;
  int head = blockIdx.y >> 1;
  int c0 = (blockIdx.y & 1) * 64;
  bool lig = r0 < ROWS_L;
  const float* B = (head ? Bw1 : Aw1) + (lig ? 0 : DC * DC);
  const float* bp = lig ? (head ? Bb1 : Ab1) : nullptr;
  __shared__ float as_t[32][68], bs[32][68];
  int tid = threadIdx.x, tx = tid & 15, ty = tid >> 4;
  float acc[4][4];
#pragma unroll
  for (int r = 0; r < 4; ++r)
#pragma unroll
    for (int c = 0; c < 4; ++c) acc[r][c] = 0.f;
  for (int kc = 0; kc < DC; kc += 32) {
    __syncthreads();
    for (int t = tid; t < 2048; t += 256) {
      int kk = t & 31, rr = t >> 5;
      as_t[kk][rr] = X[(long)(r0 + rr) * DC + kc + kk];
    }
    for (int t = tid; t < 2048; t += 256) {
      int cc = t & 63, kk = t >> 6;
      bs[kk][cc] = B[(long)(kc + kk) * DC + c0 + cc];
    }
    __syncthreads();
#pragma unroll
    for (int kk = 0; kk < 32; ++kk) {
      float4 a = *(const float4*)&as_t[kk][ty * 4];
      float4 bv = *(const float4*)&bs[kk][tx * 4];
      acc[0][0] = fmaf(a.x, bv.x, acc[0][0]);
      acc[0][1] = fmaf(a.x, bv.y, acc[0][1]);
      acc[0][2] = fmaf(a.x, bv.z, acc[0][2]);
      acc[0][3] = fmaf(a.x, bv.w, acc[0][3]);
      acc[1][0] = fmaf(a.y, bv.x, acc[1][0]);
      acc[1][1] = fmaf(a.y, bv.y, acc[1][1]);
      acc[1][2] = fmaf(a.y, bv.z, acc[1][2]);
      acc[1][3] = fmaf(a.y, bv.w, acc[1][3]);
      acc[2][0] = fmaf(a.z, bv.x, acc[2][0]);
      acc[2][1] = fmaf(a.z, bv.y, acc[2][1]);
      acc[2][2] = fmaf(a.z, bv.z, acc[2][2]);
      acc[2][3] = fmaf(a.z, bv.w, acc[2][3]);
      acc[3][0] = fmaf(a.w, bv.x, acc[3][0]);
      acc[3][1] = fmaf(a.w, bv.y, acc[3][1]);
      acc[3][2] = fmaf(a.w, bv.z, acc[3][2]);
      acc[3][3] = fmaf(a.w, bv.w, acc[3][3]);
    }
  }
  if (lig) {
    float* Y = head ? UB : UA;
    float bvv[4];
#pragma unroll
    for (int c = 0; c < 4; ++c) bvv[c] = bp[c0 + tx * 4 + c];
#pragma unroll
    for (int r = 0; r < 4; ++r) {
      float4 o;
      o.x = acc[r][0] + bvv[0];
      o.y = acc[r][1] + bvv[1];
      o.z = acc[r][2] + bvv[2];
      o.w = acc[r][3] + bvv[3];
      *(float4*)&Y[(long)(r0 + ty * 4 + r) * DC + c0 + tx * 4] = o;
    }
  } else {
    float* V = head ? VBT : VAT;
    int bb = (r0 - ROWS_L) >> 8;
    int jb = (r0 - ROWS_L) & 255;
#pragma unroll
    for (int c = 0; c < 4; ++c) {
      int colg = c0 + tx * 4 + c;
      float4 o;
      o.x = acc[0][c];
      o.y = acc[1][c];
      o.z = acc[2][c];
      o.w = acc[3][c];
      *(float4*)&V[((long)bb * DC + colg) * N2C + jb + ty * 4] = o;
    }
  }
}

// ---------------------------------------------------------------------------
// Pairwise physics + analytic grad/Hessian partials (verified).
// ---------------------------------------------------------------------------
__global__ __launch_bounds__(256) void k_pair(
    const float* __restrict__ UA, const float* __restrict__ VAT,
    const float* __restrict__ UB, const float* __restrict__ VBT,
    const float* __restrict__ AW2, const float* __restrict__ AB2,
    const float* __restrict__ BW2, const float* __restrict__ BB2,
    const float* __restrict__ LP, const float* __restrict__ TP,
    const float* __restrict__ LVDW, const float* __restrict__ TVDW,
    const float* __restrict__ LNM, const float* __restrict__ TNM,
    const float* __restrict__ II, const float* __restrict__ HBC,
    const float* __restrict__ HPC, float* __restrict__ PART) {
  const int D = DC, N1 = N1C, N2 = N2C;
  int i = blockIdx.x, b = blockIdx.y, j = threadIdx.x;
  __shared__ float ua[128], ub[128], wa2[128], wb2[128];
  if (j < 128) {
    long rb = ((long)b * N1 + i) * D + j;
    ua[j] = UA[rb];
    ub[j] = UB[rb];
    wa2[j] = AW2[j];
    wb2[j] = BW2[j];
  }
  __syncthreads();
  const float* vat = VAT + (long)b * D * N2;
  const float* vbt = VBT + (long)b * D * N2;
  float dotA = 0.f, dotB = 0.f;
#pragma unroll 8
  for (int d = 0; d < D; ++d) {
    dotA += fmaxf(ua[d] + vat[(long)d * N2 + j], 0.f) * wa2[d];
    dotB += fmaxf(ub[d] + vbt[(long)d * N2 + j], 0.f) * wb2[d];
  }
  float A_raw = 1.f / (1.f + expf(-(dotA + AB2[0])));
  float A_vdw = A_raw * (0.0356f - 0.0178f) + 0.0178f;
  float B_raw = tanhf(dotB + BB2[0]) * 0.2f;

  float lx = LP[((long)b * N1 + i) * 3 + 0];
  float ly = LP[((long)b * N1 + i) * 3 + 1];
  float lz = LP[((long)b * N1 + i) * 3 + 2];
  float tx = TP[((long)b * N2 + j) * 3 + 0];
  float ty = TP[((long)b * N2 + j) * 3 + 1];
  float tz = TP[((long)b * N2 + j) * 3 + 2];
  float dx = lx - tx, dy = ly - ty, dz = lz - tz;
  float s2 = dx * dx + dy * dy + dz * dz + 1e-10f;
  float draw = sqrtf(s2);
  bool clamped = draw < 0.5f;
  float dmv = clamped ? 1e10f : draw;

  float dm0 = LVDW[b * N1 + i] + TVDW[b * N2 + j] + B_raw;
  float dm0c = (dm0 < 1e-4f) ? 1.f : dm0;
  float valid = LNM[b * N1 + i] * TNM[b * N2 + j];

  float rr = dm0c / dmv;
  float r2 = rr * rr, r6 = r2 * r2 * r2;
  float fv = r6 * r6 - 2.f * r6;
  float evdw = A_vdw * (fminf(fv, 100.f) * valid);

  float dmd = dmv - dm0;
  long ii0 = ((long)b * 3) * N1 * N2 + (long)i * N2 + j;
  float I0 = II[ii0];
  float I1 = II[ii0 + (long)N1 * N2];
  float I2 = II[ii0 + 2L * N1 * N2];
  float hb2 = HBC[0] * HBC[0], hp2 = HPC[0] * HPC[0];
  float u0 = dmd * I0 / (-0.7f);
  float u1 = dmd * I1 / (-0.7f);
  float vv = (1.5f - dmd) * I2;
  float ehb = fminf(fmaxf(u0, 0.f), 1.f) * (-hb2);
  float emt = fminf(fmaxf(u1, 0.f), 1.f) * (-hb2);
  float ehp = fminf(fmaxf(vv, 0.f), 1.f) * (-hp2);

  float gx = 0.f, gy = 0.f, gz = 0.f, d2t = 0.f;
  if (!clamped) {
    float Ep = 0.f, Epp = 0.f;
    if (fv < 100.f) {
      float c = A_vdw * valid;
      Ep += c * (-12.f) * r6 * (r6 - 1.f) / draw;
      Epp += c * r6 * (156.f * r6 - 84.f) / s2;
    }
    if (u0 > 0.f && u0 < 1.f) Ep += hb2 * I0 * (1.f / 0.7f);
    if (u1 > 0.f && u1 < 1.f) Ep += hb2 * I1 * (1.f / 0.7f);
    if (vv > 0.f && vv < 1.f) Ep += hp2 * I2;
    float invd = 1.f / draw;
    gx = Ep * dx * invd;
    gy = Ep * dy * invd;
    gz = Ep * dz * invd;
    float T = dx + dy + dz;
    float tt = T * T / s2;
    d2t = Epp * tt + Ep * (3.f - tt) * invd;
  }

  float o0 = blockSum(evdw);
  float o1 = blockSum(ehb);
  float o2 = blockSum(emt);
  float o3 = blockSum(ehp);
  float o4 = blockSum(gx);
  float o5 = blockSum(gy);
  float o6 = blockSum(gz);
  float o7 = blockSum(d2t);
  if (j == 0) {
    float* p = PART + ((long)b * N1 + i) * 8;
    p[0] = o0; p[1] = o1; p[2] = o2; p[3] = o3;
    p[4] = o4; p[5] = o5; p[6] = o6; p[7] = o7;
  }
}

// final deterministic reduction + output assembly (34 floats)
__global__ void k_final(const float* __restrict__ PART, const float* __restrict__ ROT,
                        const float* __restrict__ RC, float* __restrict__ OUT) {
  const int N1 = N1C;
  __shared__ float s[8][8];
  int t = threadIdx.x;
  if (t < 64) {
    int b = t >> 3, k1 = t & 7;
    float acc = 0.f;
    for (int i = 0; i < N1; ++i) acc += PART[((long)b * N1 + i) * 8 + k1];
    s[b][k1] = acc;
  }
  __syncthreads();
  if (t == 0) {
    float rcc = RC[0] * RC[0];
    float der1 = 0.f, der2 = 0.f;
    for (int b = 0; b < 8; ++b) {
      float w = 1.f / (1.f + rcc * ROT[b]);
      OUT[b * 4 + 0] = s[b][0] * w;
      OUT[b * 4 + 1] = s[b][1] * w;
      OUT[b * 4 + 2] = s[b][2] * w;
      OUT[b * 4 + 3] = s[b][3] * w;
      for (int c = 0; c < 3; ++c) {
        float S = s[b][4 + c] * w;
        der1 += S * S;
      }
      der2 += s[b][7] * w;
    }
    OUT[32] = der1 / 24.f;
    OUT[33] = -der2 / 8.f;
  }
}

// ---------------------------------------------------------------------------
// Host-side orchestration
// ---------------------------------------------------------------------------
extern "C" void kernel_launch(void* const* d_in, const int* in_sizes, int n_in,
                              void* d_out, int out_size, void* d_ws, size_t ws_size,
                              hipStream_t stream) {
  (void)in_sizes; (void)n_in; (void)out_size; (void)ws_size;
  const int D = DC;

  const float* ligand_h   = (const float*)d_in[0];
  const float* ligand_adj = (const float*)d_in[1];
  const float* target_h   = (const float*)d_in[2];
  const float* target_adj = (const float*)d_in[3];
  const float* inter_ind  = (const float*)d_in[4];
  const float* ligand_pos = (const float*)d_in[5];
  const float* target_pos = (const float*)d_in[6];
  const float* rotor      = (const float*)d_in[7];
  const float* lvdw       = (const float*)d_in[8];
  const float* tvdw       = (const float*)d_in[9];
  const float* lnm        = (const float*)d_in[12];
  const float* tnm        = (const float*)d_in[13];
  const float* emb_w      = (const float*)d_in[14];
  const float* gat_w      = (const float*)d_in[15];
  const float* gat_b      = (const float*)d_in[16];
  const float* gat_att    = (const float*)d_in[17];
  const float* gat_gate_w = (const float*)d_in[18];
  const float* gat_gate_b = (const float*)d_in[19];
  const float* int_wt_w   = (const float*)d_in[20];
  const float* int_wt_b   = (const float*)d_in[21];
  const float* int_mt_w   = (const float*)d_in[22];
  const float* int_mt_b   = (const float*)d_in[23];
  const float* gru_w_ih   = (const float*)d_in[24];
  const float* gru_w_hh   = (const float*)d_in[25];
  const float* gru_b_ih   = (const float*)d_in[26];
  const float* gru_b_hh   = (const float*)d_in[27];
  const float* A_w1       = (const float*)d_in[28];
  const float* A_b1       = (const float*)d_in[29];
  const float* A_w2       = (const float*)d_in[30];
  const float* A_b2       = (const float*)d_in[31];
  const float* B_w1       = (const float*)d_in[32];
  const float* B_b1       = (const float*)d_in[33];
  const float* B_w2       = (const float*)d_in[34];
  const float* B_b2       = (const float*)d_in[35];
  const float* hb_c       = (const float*)d_in[36];
  const float* hp_c       = (const float*)d_in[37];
  const float* rc_c       = (const float*)d_in[38];

  // workspace carve (floats)
  float* w = (float*)d_ws;
  auto take = [&](size_t n) { float* p = w; w += n; return p; };
  float* H0    = take((size_t)ROWS_ALL * DC);   // 393216
  float* H1    = take((size_t)ROWS_ALL * DC);
  float* NT    = take((size_t)ROWS_ALL * DC);
  float* E1    = take((size_t)ROWS_ALL * DC);
  float* EAL   = take((size_t)BB * N1C * N1C);  // 131072
  float* EAT   = take((size_t)BB * N2C * N2C);  // 524288
  float* ADJ12 = take((size_t)BB * N1C * N2C);  // 262144
  float* WA    = take((size_t)3 * DC * DC);     // 49152
  float* bA    = take((size_t)3 * DC);
  float* GIHT  = take((size_t)3 * DC * 384);    // 147456
  float* GHHT  = take((size_t)3 * DC * 384);
  float* PART  = take((size_t)BB * N1C * 8);
  float* GI    = take((size_t)ROWS_ALL * 384);  // 1179648
  float* GH    = take((size_t)ROWS_ALL * 384);
  // phase-disjoint aliases
  float* T1  = NT;
  float* M2  = E1;
  float* MSG = EAT;           // 393216 <= 524288
  float* UA  = EAL;           // 131072
  float* UB  = EAT;           // 131072 (front of EAT)
  float* VAT = NT;            // 262144 <= 393216
  float* VBT = E1;            // 262144

  // merged prep: adj12 + embedding + WA fuse + GRU weight transposes
  k_prep<<<2659, 256, 0, stream>>>(ligand_pos, target_pos, ADJ12, ligand_h,
                                   target_h, emb_w, H0, gat_w, gat_b, gat_att,
                                   WA, bA, gru_w_ih, gru_w_hh, GIHT, GHHT);

  float *cur = H0, *alt = H1;

  // GAT stack (3 layers)
  for (int l = 0; l < 3; ++l) {
    k_gemm2w<<<dim3(48, 4), 256, 0, stream>>>(
        cur, gat_w + (size_t)l * D * D, gat_b + l * D, WA + (size_t)l * D * D,
        bA + l * D, NT, E1);
    k_gemmS<<<160, 256, 0, stream>>>(E1, NT, EAL, EAT);
    k_smagg2<<<dim3(16, 8, 2), 256, 0, stream>>>(
        EAL, EAT, ligand_adj, target_adj, NT, cur, gat_gate_w + l * 2 * D,
        gat_gate_b + l, alt);
    float* t = cur; cur = alt; alt = t;
  }

  // interaction layers (both directions use OLD h)
  for (int l = 0; l < 3; ++l) {
    k_gemm2w<<<dim3(48, 4), 256, 0, stream>>>(
        cur, int_wt_w + (size_t)l * D * D, int_wt_b + l * D,
        int_mt_w + (size_t)l * D * D, int_mt_b + l * D, T1, M2);
    k_msg2v<<<dim3(32, 8, 2), 256, 0, stream>>>(T1, M2, ADJ12, MSG);
    k_ggru<<<dim3(24, 6), 256, 0, stream>>>(MSG, cur, GIHT + (size_t)l * D * 384,
                                            GHHT + (size_t)l * D * 384,
                                            gru_b_ih + l * 384,
                                            gru_b_hh + l * 384, GI, GH);
    k_comb<<<384, 256, 0, stream>>>(GI, GH, cur, alt);
    float* t = cur; cur = alt; alt = t;
  }

  // pairwise feature heads (U normal layout, V transposed [b][d][j])
  k_featg<<<dim3(48, 4), 256, 0, stream>>>(cur, A_w1, A_b1, B_w1, B_b1, UA, UB,
                                           VAT, VBT);

  // pairwise physics + analytic derivatives
  k_pair<<<dim3(N1C, BB), 256, 0, stream>>>(UA, VAT, UB, VBT, A_w2, A_b2, B_w2,
                                            B_b2, ligand_pos, target_pos, lvdw,
                                            tvdw, lnm, tnm, inter_ind, hb_c,
                                            hp_c, PART);

  // final reduction -> 34 outputs
  k_final<<<1, 256, 0, stream>>>(PART, rotor, rc_c, (float*)d_out);
}

// Round 8
// 351.235 us; speedup vs baseline: 1.4816x; 1.4816x over previous
//
#include <hip/hip_runtime.h>
#include <math.h>

// ---------------------------------------------------------------------------
// Problem constants (B=8, N1=128, N2=256, D=128, L=3, NH=54)
// Packed row space: rows 0..1023 = ligand (b*128+i), rows 1024..3071 = target
// (1024 + b*256 + j).
// ---------------------------------------------------------------------------
#define BB 8
#define N1C 128
#define N2C 256
#define DC 128
#define NHC 54
#define ROWS_L 1024
#define ROWS_T 2048
#define ROWS_ALL 3072

// ---------------------------------------------------------------------------
// Reductions (wave64)
// ---------------------------------------------------------------------------
__device__ __forceinline__ float wredSum(float v) {
#pragma unroll
  for (int o = 32; o > 0; o >>= 1) v += __shfl_down(v, o);
  return v;
}
__device__ float blockSum(float v) {
  __shared__ float red[9];
  v = wredSum(v);
  int lane = threadIdx.x & 63, wid = threadIdx.x >> 6;
  __syncthreads();
  if (lane == 0) red[wid] = v;
  __syncthreads();
  if (threadIdx.x == 0) {
    float s = 0.f;
    int nw = (blockDim.x + 63) >> 6;
    for (int i = 0; i < nw; ++i) s += red[i];
    red[8] = s;
  }
  __syncthreads();
  return red[8];
}

// ---------------------------------------------------------------------------
// k_prep: merged adj12 + embedding + GAT-weight-fuse + GRU-weight-transpose.
// grid = 1024 + 384 + 99 + 1152 = 2659 blocks, 256 threads.
// ---------------------------------------------------------------------------
__global__ __launch_bounds__(256) void k_prep(
    const float* __restrict__ LP, const float* __restrict__ TP,
    float* __restrict__ AD, const float* __restrict__ LH,
    const float* __restrict__ TH, const float* __restrict__ EW,
    float* __restrict__ H0, const float* __restrict__ GWp,
    const float* __restrict__ GBp, const float* __restrict__ ATT,
    float* __restrict__ WA, float* __restrict__ bA,
    const float* __restrict__ IH, const float* __restrict__ HH,
    float* __restrict__ GIHT, float* __restrict__ GHHT) {
  int bid = blockIdx.x, tid = threadIdx.x;
  if (bid < 1024) {  // ---- adj12 ----
    long idx = (long)bid * 256 + tid;
    int j = idx & (N2C - 1);
    long t = idx >> 8;
    int i = (int)(t & (N1C - 1));
    int b = (int)(t >> 7);
    float dx = LP[((long)b * N1C + i) * 3 + 0] - TP[((long)b * N2C + j) * 3 + 0];
    float dy = LP[((long)b * N1C + i) * 3 + 1] - TP[((long)b * N2C + j) * 3 + 1];
    float dz = LP[((long)b * N1C + i) * 3 + 2] - TP[((long)b * N2C + j) * 3 + 2];
    float d = sqrtf(dx * dx + dy * dy + dz * dz + 1e-10f);
    if (d < 0.5f) d = 1e10f;
    AD[idx] = (d <= 5.0f && d > 1e-3f) ? 1.f : 0.f;
  } else if (bid < 1024 + 384) {  // ---- embedding, 8 rows/block ----
    int r0 = (bid - 1024) * 8;
    __shared__ float xs[8][NHC];
    for (int t = tid; t < 8 * NHC; t += 256) {
      int rr = r0 + t / NHC, c = t % NHC;
      xs[t / NHC][c] = (rr < ROWS_L) ? LH[(long)rr * NHC + c]
                                     : TH[(long)(rr - ROWS_L) * NHC + c];
    }
    __syncthreads();
    int d = tid & 127, rb = (tid >> 7) * 4;
    float a[4] = {0.f, 0.f, 0.f, 0.f};
#pragma unroll 6
    for (int k = 0; k < NHC; ++k) {
      float wv = EW[(long)k * DC + d];
#pragma unroll
      for (int r = 0; r < 4; ++r) a[r] += xs[rb + r][k] * wv;
    }
#pragma unroll
    for (int r = 0; r < 4; ++r) H0[(long)(r0 + rb + r) * DC + d] = a[r];
  } else if (bid < 1024 + 384 + 99) {  // ---- wfuse: WA_l = W_l @ ATT_l ----
    int q = bid - 1408;
    int l = q / 33, bx = q % 33;
    const float* Wl = GWp + (long)l * DC * DC;
    const float* Al = ATT + (long)l * DC * DC;
    if (bx == 32) {
      if (tid < 128) {
        float acc = 0.f;
#pragma unroll 8
        for (int m = 0; m < DC; ++m)
          acc += GBp[l * DC + m] * Al[(long)m * DC + tid];
        bA[l * DC + tid] = acc;
      }
    } else {
      __shared__ float xs2[4][DC];
      int r0 = bx * 4;
      for (int t = tid; t < 4 * DC; t += 256)
        xs2[t >> 7][t & 127] = Wl[(long)r0 * DC + t];
      __syncthreads();
      if (tid < 128) {
        int d = tid;
        float a0 = 0.f, a1 = 0.f, a2 = 0.f, a3 = 0.f;
#pragma unroll 8
        for (int m = 0; m < DC; ++m) {
          float av = Al[(long)m * DC + d];
          a0 += xs2[0][m] * av;
          a1 += xs2[1][m] * av;
          a2 += xs2[2][m] * av;
          a3 += xs2[3][m] * av;
        }
        float* out = WA + (long)l * DC * DC + (long)r0 * DC + d;
        out[0] = a0;
        out[DC] = a1;
        out[2 * DC] = a2;
        out[3 * DC] = a3;
      }
    }
  } else {  // ---- GRU weight transposes ----
    long idx = (long)(bid - 1507) * 256 + tid;
    if (idx < 6L * 49152) {
      int a = (int)(idx / 49152);
      int rem = (int)(idx % 49152);
      int l = a >> 1, whh = a & 1;
      int c = rem / 384, rr = rem % 384;
      const float* src = (whh ? HH : IH) + (long)l * 49152;
      float* dst = (whh ? GHHT : GIHT) + (long)l * 49152;
      dst[(long)c * 384 + rr] = src[(long)rr * 128 + c];
    }
  }
}

// ---------------------------------------------------------------------------
// Dual-head linear: Y1 = X@W1(+b1), Y2 = X@W2(+b2).  4 rows/block, 256 thr
// (tid>>7 = head, d = tid&127).  X staged TRANSPOSED -> one b128 broadcast
// per k instead of 4 scalar LDS reads.  trans=1 stores Yh[b][d][row].
// ---------------------------------------------------------------------------
__global__ __launch_bounds__(256) void k_lin2h(
    const float* __restrict__ X, const float* __restrict__ W1,
    const float* __restrict__ b1, const float* __restrict__ W2,
    const float* __restrict__ b2, float* __restrict__ Y1, float* __restrict__ Y2,
    int rpb, int trans) {
  int r0 = blockIdx.x * 4;
  __shared__ float xs_t[DC][4];
  int tid = threadIdx.x;
  for (int t = tid; t < 4 * DC; t += 256) {
    int r = t >> 7, c = t & 127;
    xs_t[c][r] = X[(long)(r0 + r) * DC + c];
  }
  __syncthreads();
  int h = tid >> 7, d = tid & 127;
  const float* W = h ? W2 : W1;
  const float* bp = h ? b2 : b1;
  float* Y = h ? Y2 : Y1;
  float a0 = 0.f, a1 = 0.f, a2 = 0.f, a3 = 0.f;
#pragma unroll 8
  for (int k = 0; k < DC; ++k) {
    float4 xv = *(const float4*)&xs_t[k][0];
    float wv = W[(long)k * DC + d];
    a0 = fmaf(xv.x, wv, a0);
    a1 = fmaf(xv.y, wv, a1);
    a2 = fmaf(xv.z, wv, a2);
    a3 = fmaf(xv.w, wv, a3);
  }
  float bv = bp ? bp[d] : 0.f;
  float v[4] = {a0 + bv, a1 + bv, a2 + bv, a3 + bv};
  if (!trans) {
#pragma unroll
    for (int r = 0; r < 4; ++r) Y[(long)(r0 + r) * DC + d] = v[r];
  } else {
    int b = r0 / rpb, rin = r0 - b * rpb;  // 4 | rpb, so same batch
#pragma unroll
    for (int r = 0; r < 4; ++r)
      Y[((long)b * DC + d) * rpb + rin + r] = v[r];
  }
}

// ---------------------------------------------------------------------------
// k_ea2: ea[b,j,k] = e1_j.nt_k + nt_j.e1_k, masked by adjacency at write.
// Register-tiled: 32x64 tile, 256 thr, 2x4 outputs/thread.  Merged
// ligand+target: 64 + 256 = 320 blocks.
// ---------------------------------------------------------------------------
__global__ __launch_bounds__(256) void k_ea2(const float* __restrict__ NTp,
                                             const float* __restrict__ E1p,
                                             const float* __restrict__ ADJL,
                                             const float* __restrict__ ADJT,
                                             float* __restrict__ EAL,
                                             float* __restrict__ EAT) {
  int id = blockIdx.x;
  int N, base, j0, k0, b;
  const float* ADJ;
  float* EA;
  if (id < 64) {
    b = id >> 3;
    int rem = id & 7;
    N = N1C;
    base = b * N1C;
    j0 = (rem >> 1) * 32;
    k0 = (rem & 1) * 64;
    ADJ = ADJL + (long)b * N1C * N1C;
    EA = EAL + (long)b * N1C * N1C;
  } else {
    int q = id - 64;
    b = q >> 5;
    int rem = q & 31;
    N = N2C;
    base = ROWS_L + b * N2C;
    j0 = (rem >> 2) * 32;
    k0 = (rem & 3) * 64;
    ADJ = ADJT + (long)b * N2C * N2C;
    EA = EAT + (long)b * N2C * N2C;
  }
  __shared__ float aj_e1[32][34], aj_nt[32][34];
  __shared__ float bk_e1[32][68], bk_nt[32][68];
  int tid = threadIdx.x, tx = tid & 15, ty = tid >> 4;
  float acc[2][4];
#pragma unroll
  for (int r = 0; r < 2; ++r)
#pragma unroll
    for (int c = 0; c < 4; ++c) acc[r][c] = 0.f;
  for (int kc = 0; kc < DC; kc += 32) {
    __syncthreads();
    for (int t = tid; t < 1024; t += 256) {
      int kk = t & 31, rr = t >> 5;
      aj_e1[kk][rr] = E1p[(long)(base + j0 + rr) * DC + kc + kk];
      aj_nt[kk][rr] = NTp[(long)(base + j0 + rr) * DC + kc + kk];
    }
    for (int t = tid; t < 2048; t += 256) {
      int kk = t & 31, cc = t >> 5;
      bk_e1[kk][cc] = E1p[(long)(base + k0 + cc) * DC + kc + kk];
      bk_nt[kk][cc] = NTp[(long)(base + k0 + cc) * DC + kc + kk];
    }
    __syncthreads();
#pragma unroll
    for (int kk = 0; kk < 32; ++kk) {
      float2 ae = *(const float2*)&aj_e1[kk][ty * 2];
      float2 an = *(const float2*)&aj_nt[kk][ty * 2];
      float4 bn = *(const float4*)&bk_nt[kk][tx * 4];
      float4 be = *(const float4*)&bk_e1[kk][tx * 4];
      acc[0][0] = fmaf(ae.x, bn.x, fmaf(an.x, be.x, acc[0][0]));
      acc[0][1] = fmaf(ae.x, bn.y, fmaf(an.x, be.y, acc[0][1]));
      acc[0][2] = fmaf(ae.x, bn.z, fmaf(an.x, be.z, acc[0][2]));
      acc[0][3] = fmaf(ae.x, bn.w, fmaf(an.x, be.w, acc[0][3]));
      acc[1][0] = fmaf(ae.y, bn.x, fmaf(an.y, be.x, acc[1][0]));
      acc[1][1] = fmaf(ae.y, bn.y, fmaf(an.y, be.y, acc[1][1]));
      acc[1][2] = fmaf(ae.y, bn.z, fmaf(an.y, be.z, acc[1][2]));
      acc[1][3] = fmaf(ae.y, bn.w, fmaf(an.y, be.w, acc[1][3]));
    }
  }
#pragma unroll
  for (int r = 0; r < 2; ++r) {
    long rowi = (long)(j0 + ty * 2 + r) * N + k0 + tx * 4;
    float4 ad = *(const float4*)&ADJ[rowi];
    float4 o;
    o.x = (ad.x > 1e-6f) ? acc[r][0] : -9e15f;
    o.y = (ad.y > 1e-6f) ? acc[r][1] : -9e15f;
    o.z = (ad.z > 1e-6f) ? acc[r][2] : -9e15f;
    o.w = (ad.w > 1e-6f) ? acc[r][3] : -9e15f;
    *(float4*)&EA[rowi] = o;
  }
}

// ---------------------------------------------------------------------------
// Merged (ligand+target) fused row-softmax + aggregate + gated residual.
// z=0: ligand (N=128, EAL), z=1: target (N=256, EAT).  8 rows/block,
// 512 threads.  Y = g*x + (1-g)*relu(P@NT).   (round-6 verified version)
// ---------------------------------------------------------------------------
__global__ __launch_bounds__(512) void k_smagg(
    const float* __restrict__ EAL, const float* __restrict__ EAT,
    const float* __restrict__ NTp, const float* __restrict__ Xp,
    const float* __restrict__ GW, const float* __restrict__ GB,
    float* __restrict__ Y) {
  int z = blockIdx.z;
  int N = z ? N2C : N1C;
  if (blockIdx.x * 8 >= N) return;
  int ls = z ? 8 : 7;
  int baseRow = z ? ROWS_L : 0;
  const float* EA = z ? EAT : EAL;
  int b = blockIdx.y, i0 = blockIdx.x * 8;
  __shared__ float ps[8][N2C + 4];
  __shared__ float col[32][DC + 4];
  __shared__ float red[8][2];
  int tid = threadIdx.x;
  const float* EAb = EA + (long)b * N * N + (long)i0 * N;
  for (int t = tid; t < 8 * N; t += 512)
    ps[t >> ls][t & (N - 1)] = EAb[t];
  __syncthreads();
  {  // softmax: 64 lanes per row
    int r = tid >> 6, l = tid & 63;
    float m = -INFINITY;
    for (int k = l; k < N; k += 64) m = fmaxf(m, ps[r][k]);
#pragma unroll
    for (int o = 32; o > 0; o >>= 1) m = fmaxf(m, __shfl_xor(m, o));
    float s = 0.f;
    for (int k = l; k < N; k += 64) {
      float p = expf(ps[r][k] - m);
      ps[r][k] = p;
      s += p;
    }
#pragma unroll
    for (int o = 32; o > 0; o >>= 1) s += __shfl_xor(s, o);
    float inv = 1.f / s;
    for (int k = l; k < N; k += 64) ps[r][k] *= inv;
  }
  // aggregate: d = tid&127, group ro = tid>>7 handles rows ro and ro+4
  int d = tid & 127, ro = tid >> 7;
  float acc[2] = {0.f, 0.f};
  const float* NTb = NTp + (long)(baseRow + b * N) * DC;
  for (int k0 = 0; k0 < N; k0 += 32) {
    __syncthreads();
    for (int t = tid; t < 32 * DC; t += 512)
      col[t >> 7][t & 127] = NTb[(long)(k0 + (t >> 7)) * DC + (t & 127)];
    __syncthreads();
#pragma unroll 8
    for (int kk = 0; kk < 32; ++kk) {
      float cv = col[kk][d];
      acc[0] = fmaf(ps[ro][k0 + kk], cv, acc[0]);
      acc[1] = fmaf(ps[ro + 4][k0 + kk], cv, acc[1]);
    }
  }
  // fused gate
  float gwd = GW[d], gwo = GW[DC + d];
  float xv[2], ov[2], part[2];
#pragma unroll
  for (int q = 0; q < 2; ++q) {
    int r = ro + 4 * q;
    float o = fmaxf(acc[q], 0.f);
    ov[q] = o;
    float x = Xp[(long)(baseRow + b * N + i0 + r) * DC + d];
    xv[q] = x;
    part[q] = x * gwd + o * gwo;
  }
  int wid = tid >> 6;
#pragma unroll
  for (int q = 0; q < 2; ++q) {
    float v = wredSum(part[q]);
    if ((tid & 63) == 0) red[wid][q] = v;
  }
  __syncthreads();
  float gb = GB[0];
#pragma unroll
  for (int q = 0; q < 2; ++q) {
    int r = ro + 4 * q;
    float s = red[2 * ro][q] + red[2 * ro + 1][q];
    float g = 1.f / (1.f + expf(-(s + gb)));
    Y[(long)(baseRow + b * N + i0 + r) * DC + d] = g * xv[q] + (1.f - g) * ov[q];
  }
}

// ---------------------------------------------------------------------------
// k_msg2v: msg = relu(t1 + max_j m2_j * ev_ij).  8 rows/block, 256 thr
// (32 dgrp x 8 rows).  grid (32, 8, 2): z=0 ligand (x<16), z=1 target.
// ---------------------------------------------------------------------------
__global__ __launch_bounds__(256) void k_msg2v(const float* __restrict__ T1,
                                               const float* __restrict__ M2,
                                               const float* __restrict__ EV,
                                               float* __restrict__ MSG) {
  int z = blockIdx.z, b = blockIdx.y;
  int Ni = z ? N2C : N1C, Nj = z ? N1C : N2C;
  if (blockIdx.x * 8 >= Ni) return;
  int t1off = z ? ROWS_L : 0, m2off = z ? 0 : ROWS_L;
  long ev_is = z ? 1L : (long)N2C, ev_js = z ? (long)N2C : 1L;
  int i0 = blockIdx.x * 8;
  __shared__ float m2s[32][DC + 4];
  __shared__ float evs[8][36];
  int dgrp = threadIdx.x & 31, row = threadIdx.x >> 5;
  int d0 = dgrp * 4;
  float a0 = -INFINITY, a1 = -INFINITY, a2 = -INFINITY, a3 = -INFINITY;
  const float* M2b = M2 + (long)(m2off + b * Nj) * DC;
  const float* EVb = EV + (long)b * (N1C * N2C);
  for (int j0 = 0; j0 < Nj; j0 += 32) {
    __syncthreads();
    for (int t = threadIdx.x; t < 32 * DC; t += 256)
      m2s[t >> 7][t & 127] = M2b[(long)(j0 + (t >> 7)) * DC + (t & 127)];
    for (int t = threadIdx.x; t < 256; t += 256)
      evs[t >> 5][t & 31] =
          EVb[(long)(i0 + (t >> 5)) * ev_is + (long)(j0 + (t & 31)) * ev_js];
    __syncthreads();
#pragma unroll 8
    for (int jj = 0; jj < 32; ++jj) {
      float4 m4 = *(const float4*)&m2s[jj][d0];
      float e = evs[row][jj];
      a0 = fmaxf(a0, m4.x * e);
      a1 = fmaxf(a1, m4.y * e);
      a2 = fmaxf(a2, m4.z * e);
      a3 = fmaxf(a3, m4.w * e);
    }
  }
  long grow = t1off + (long)b * Ni + i0 + row;
  float4 t4 = *(const float4*)&T1[grow * DC + d0];
  float4 o;
  o.x = fmaxf(t4.x + a0, 0.f);
  o.y = fmaxf(t4.y + a1, 0.f);
  o.z = fmaxf(t4.z + a2, 0.f);
  o.w = fmaxf(t4.w + a3, 0.f);
  *(float4*)&MSG[grow * DC + d0] = o;
}

// ---------------------------------------------------------------------------
// Fused GRU, 4 rows/block (768 blocks), 384 threads (round-6 verified).
// ---------------------------------------------------------------------------
__global__ __launch_bounds__(384) void k_gruf(
    const float* __restrict__ MSGp, const float* __restrict__ Hp,
    const float* __restrict__ WihT, const float* __restrict__ WhhT,
    const float* __restrict__ bih, const float* __restrict__ bhh,
    float* __restrict__ Y) {
  const int D = DC;
  int r0 = blockIdx.x * 4;
  __shared__ float xs_t[DC][4], hs_t[DC][4];
  __shared__ float gis[4][384], ghs[4][384];
  int tid = threadIdx.x;
  for (int t = tid; t < 4 * DC; t += 384) {
    int r = t >> 7, c = t & 127;
    xs_t[c][r] = MSGp[(long)(r0 + r) * D + c];
    hs_t[c][r] = Hp[(long)(r0 + r) * D + c];
  }
  __syncthreads();
  int dd = tid;  // 0..383
  float ai[4] = {0.f, 0.f, 0.f, 0.f}, ah[4] = {0.f, 0.f, 0.f, 0.f};
#pragma unroll 8
  for (int k = 0; k < DC; ++k) {
    float4 xv = *reinterpret_cast<const float4*>(&xs_t[k][0]);
    float4 hv = *reinterpret_cast<const float4*>(&hs_t[k][0]);
    float wi = WihT[(long)k * 384 + dd];
    float wh = WhhT[(long)k * 384 + dd];
    ai[0] = fmaf(xv.x, wi, ai[0]);
    ai[1] = fmaf(xv.y, wi, ai[1]);
    ai[2] = fmaf(xv.z, wi, ai[2]);
    ai[3] = fmaf(xv.w, wi, ai[3]);
    ah[0] = fmaf(hv.x, wh, ah[0]);
    ah[1] = fmaf(hv.y, wh, ah[1]);
    ah[2] = fmaf(hv.z, wh, ah[2]);
    ah[3] = fmaf(hv.w, wh, ah[3]);
  }
  float bi = bih[dd], bh = bhh[dd];
#pragma unroll
  for (int r = 0; r < 4; ++r) {
    gis[r][dd] = ai[r] + bi;
    ghs[r][dd] = ah[r] + bh;
  }
  __syncthreads();
  for (int t = tid; t < 4 * DC; t += 384) {
    int r = t >> 7, d = t & 127;
    float ir = gis[r][d], iz = gis[r][d + 128], inn = gis[r][d + 256];
    float hr = ghs[r][d], hz = ghs[r][d + 128], hn = ghs[r][d + 256];
    float rg = 1.f / (1.f + expf(-(ir + hr)));
    float zg = 1.f / (1.f + expf(-(iz + hz)));
    float ng = tanhf(inn + rg * hn);
    Y[(long)(r0 + r) * D + d] = (1.f - zg) * ng + zg * hs_t[d][r];
  }
}

// ---------------------------------------------------------------------------
// Pairwise physics + analytic grad/Hessian partials (verified).
// ---------------------------------------------------------------------------
__global__ __launch_bounds__(256) void k_pair(
    const float* __restrict__ UA, const float* __restrict__ VAT,
    const float* __restrict__ UB, const float* __restrict__ VBT,
    const float* __restrict__ AW2, const float* __restrict__ AB2,
    const float* __restrict__ BW2, const float* __restrict__ BB2,
    const float* __restrict__ LP, const float* __restrict__ TP,
    const float* __restrict__ LVDW, const float* __restrict__ TVDW,
    const float* __restrict__ LNM, const float* __restrict__ TNM,
    const float* __restrict__ II, const float* __restrict__ HBC,
    const float* __restrict__ HPC, float* __restrict__ PART) {
  const int D = DC, N1 = N1C, N2 = N2C;
  int i = blockIdx.x, b = blockIdx.y, j = threadIdx.x;
  __shared__ float ua[128], ub[128], wa2[128], wb2[128];
  if (j < 128) {
    long rb = ((long)b * N1 + i) * D + j;
    ua[j] = UA[rb];
    ub[j] = UB[rb];
    wa2[j] = AW2[j];
    wb2[j] = BW2[j];
  }
  __syncthreads();
  const float* vat = VAT + (long)b * D * N2;
  const float* vbt = VBT + (long)b * D * N2;
  float dotA = 0.f, dotB = 0.f;
#pragma unroll 8
  for (int d = 0; d < D; ++d) {
    dotA += fmaxf(ua[d] + vat[(long)d * N2 + j], 0.f) * wa2[d];
    dotB += fmaxf(ub[d] + vbt[(long)d * N2 + j], 0.f) * wb2[d];
  }
  float A_raw = 1.f / (1.f + expf(-(dotA + AB2[0])));
  float A_vdw = A_raw * (0.0356f - 0.0178f) + 0.0178f;
  float B_raw = tanhf(dotB + BB2[0]) * 0.2f;

  float lx = LP[((long)b * N1 + i) * 3 + 0];
  float ly = LP[((long)b * N1 + i) * 3 + 1];
  float lz = LP[((long)b * N1 + i) * 3 + 2];
  float tx = TP[((long)b * N2 + j) * 3 + 0];
  float ty = TP[((long)b * N2 + j) * 3 + 1];
  float tz = TP[((long)b * N2 + j) * 3 + 2];
  float dx = lx - tx, dy = ly - ty, dz = lz - tz;
  float s2 = dx * dx + dy * dy + dz * dz + 1e-10f;
  float draw = sqrtf(s2);
  bool clamped = draw < 0.5f;
  float dmv = clamped ? 1e10f : draw;

  float dm0 = LVDW[b * N1 + i] + TVDW[b * N2 + j] + B_raw;
  float dm0c = (dm0 < 1e-4f) ? 1.f : dm0;
  float valid = LNM[b * N1 + i] * TNM[b * N2 + j];

  float rr = dm0c / dmv;
  float r2 = rr * rr, r6 = r2 * r2 * r2;
  float fv = r6 * r6 - 2.f * r6;
  float evdw = A_vdw * (fminf(fv, 100.f) * valid);

  float dmd = dmv - dm0;
  long ii0 = ((long)b * 3) * N1 * N2 + (long)i * N2 + j;
  float I0 = II[ii0];
  float I1 = II[ii0 + (long)N1 * N2];
  float I2 = II[ii0 + 2L * N1 * N2];
  float hb2 = HBC[0] * HBC[0], hp2 = HPC[0] * HPC[0];
  float u0 = dmd * I0 / (-0.7f);
  float u1 = dmd * I1 / (-0.7f);
  float vv = (1.5f - dmd) * I2;
  float ehb = fminf(fmaxf(u0, 0.f), 1.f) * (-hb2);
  float emt = fminf(fmaxf(u1, 0.f), 1.f) * (-hb2);
  float ehp = fminf(fmaxf(vv, 0.f), 1.f) * (-hp2);

  float gx = 0.f, gy = 0.f, gz = 0.f, d2t = 0.f;
  if (!clamped) {
    float Ep = 0.f, Epp = 0.f;
    if (fv < 100.f) {
      float c = A_vdw * valid;
      Ep += c * (-12.f) * r6 * (r6 - 1.f) / draw;
      Epp += c * r6 * (156.f * r6 - 84.f) / s2;
    }
    if (u0 > 0.f && u0 < 1.f) Ep += hb2 * I0 * (1.f / 0.7f);
    if (u1 > 0.f && u1 < 1.f) Ep += hb2 * I1 * (1.f / 0.7f);
    if (vv > 0.f && vv < 1.f) Ep += hp2 * I2;
    float invd = 1.f / draw;
    gx = Ep * dx * invd;
    gy = Ep * dy * invd;
    gz = Ep * dz * invd;
    float T = dx + dy + dz;
    float tt = T * T / s2;
    d2t = Epp * tt + Ep * (3.f - tt) * invd;
  }

  float o0 = blockSum(evdw);
  float o1 = blockSum(ehb);
  float o2 = blockSum(emt);
  float o3 = blockSum(ehp);
  float o4 = blockSum(gx);
  float o5 = blockSum(gy);
  float o6 = blockSum(gz);
  float o7 = blockSum(d2t);
  if (j == 0) {
    float* p = PART + ((long)b * N1 + i) * 8;
    p[0] = o0; p[1] = o1; p[2] = o2; p[3] = o3;
    p[4] = o4; p[5] = o5; p[6] = o6; p[7] = o7;
  }
}

// final deterministic reduction + output assembly (34 floats)
__global__ void k_final(const float* __restrict__ PART, const float* __restrict__ ROT,
                        const float* __restrict__ RC, float* __restrict__ OUT) {
  const int N1 = N1C;
  __shared__ float s[8][8];
  int t = threadIdx.x;
  if (t < 64) {
    int b = t >> 3, k1 = t & 7;
    float acc = 0.f;
    for (int i = 0; i < N1; ++i) acc += PART[((long)b * N1 + i) * 8 + k1];
    s[b][k1] = acc;
  }
  __syncthreads();
  if (t == 0) {
    float rcc = RC[0] * RC[0];
    float der1 = 0.f, der2 = 0.f;
    for (int b = 0; b < 8; ++b) {
      float w = 1.f / (1.f + rcc * ROT[b]);
      OUT[b * 4 + 0] = s[b][0] * w;
      OUT[b * 4 + 1] = s[b][1] * w;
      OUT[b * 4 + 2] = s[b][2] * w;
      OUT[b * 4 + 3] = s[b][3] * w;
      for (int c = 0; c < 3; ++c) {
        float S = s[b][4 + c] * w;
        der1 += S * S;
      }
      der2 += s[b][7] * w;
    }
    OUT[32] = der1 / 24.f;
    OUT[33] = -der2 / 8.f;
  }
}

// ---------------------------------------------------------------------------
// Host-side orchestration
// ---------------------------------------------------------------------------
extern "C" void kernel_launch(void* const* d_in, const int* in_sizes, int n_in,
                              void* d_out, int out_size, void* d_ws, size_t ws_size,
                              hipStream_t stream) {
  (void)in_sizes; (void)n_in; (void)out_size; (void)ws_size;
  const int D = DC;

  const float* ligand_h   = (const float*)d_in[0];
  const float* ligand_adj = (const float*)d_in[1];
  const float* target_h   = (const float*)d_in[2];
  const float* target_adj = (const float*)d_in[3];
  const float* inter_ind  = (const float*)d_in[4];
  const float* ligand_pos = (const float*)d_in[5];
  const float* target_pos = (const float*)d_in[6];
  const float* rotor      = (const float*)d_in[7];
  const float* lvdw       = (const float*)d_in[8];
  const float* tvdw       = (const float*)d_in[9];
  const float* lnm        = (const float*)d_in[12];
  const float* tnm        = (const float*)d_in[13];
  const float* emb_w      = (const float*)d_in[14];
  const float* gat_w      = (const float*)d_in[15];
  const float* gat_b      = (const float*)d_in[16];
  const float* gat_att    = (const float*)d_in[17];
  const float* gat_gate_w = (const float*)d_in[18];
  const float* gat_gate_b = (const float*)d_in[19];
  const float* int_wt_w   = (const float*)d_in[20];
  const float* int_wt_b   = (const float*)d_in[21];
  const float* int_mt_w   = (const float*)d_in[22];
  const float* int_mt_b   = (const float*)d_in[23];
  const float* gru_w_ih   = (const float*)d_in[24];
  const float* gru_w_hh   = (const float*)d_in[25];
  const float* gru_b_ih   = (const float*)d_in[26];
  const float* gru_b_hh   = (const float*)d_in[27];
  const float* A_w1       = (const float*)d_in[28];
  const float* A_b1       = (const float*)d_in[29];
  const float* A_w2       = (const float*)d_in[30];
  const float* A_b2       = (const float*)d_in[31];
  const float* B_w1       = (const float*)d_in[32];
  const float* B_b1       = (const float*)d_in[33];
  const float* B_w2       = (const float*)d_in[34];
  const float* B_b2       = (const float*)d_in[35];
  const float* hb_c       = (const float*)d_in[36];
  const float* hp_c       = (const float*)d_in[37];
  const float* rc_c       = (const float*)d_in[38];

  // workspace carve (floats)
  float* w = (float*)d_ws;
  auto take = [&](size_t n) { float* p = w; w += n; return p; };
  float* H0    = take((size_t)ROWS_ALL * DC);   // 393216
  float* H1    = take((size_t)ROWS_ALL * DC);
  float* NT    = take((size_t)ROWS_ALL * DC);
  float* E1    = take((size_t)ROWS_ALL * DC);
  float* EAL   = take((size_t)BB * N1C * N1C);  // 131072
  float* EAT   = take((size_t)BB * N2C * N2C);  // 524288
  float* ADJ12 = take((size_t)BB * N1C * N2C);  // 262144
  float* WA    = take((size_t)3 * DC * DC);     // 49152
  float* bA    = take((size_t)3 * DC);
  float* GIHT  = take((size_t)3 * DC * 384);    // 147456
  float* GHHT  = take((size_t)3 * DC * 384);
  float* PART  = take((size_t)BB * N1C * 8);
  // phase-disjoint aliases
  float* T1  = NT;
  float* M2  = E1;
  float* MSG = EAT;           // 393216 <= 524288
  float* UA  = EAL;           // 131072
  float* UB  = EAT;           // 131072 (front of EAT)
  float* VAT = NT;            // 262144 <= 393216
  float* VBT = E1;            // 262144

  // merged prep: adj12 + embedding + WA fuse + GRU weight transposes
  k_prep<<<2659, 256, 0, stream>>>(ligand_pos, target_pos, ADJ12, ligand_h,
                                   target_h, emb_w, H0, gat_w, gat_b, gat_att,
                                   WA, bA, gru_w_ih, gru_w_hh, GIHT, GHHT);

  float *cur = H0, *alt = H1;

  // GAT stack (3 layers)
  for (int l = 0; l < 3; ++l) {
    k_lin2h<<<ROWS_ALL / 4, 256, 0, stream>>>(
        cur, gat_w + (size_t)l * D * D, gat_b + l * D, WA + (size_t)l * D * D,
        bA + l * D, NT, E1, 1, 0);
    k_ea2<<<320, 256, 0, stream>>>(NT, E1, ligand_adj, target_adj, EAL, EAT);
    k_smagg<<<dim3(N2C / 8, BB, 2), 512, 0, stream>>>(
        EAL, EAT, NT, cur, gat_gate_w + l * 2 * D, gat_gate_b + l, alt);
    float* t = cur; cur = alt; alt = t;
  }

  // interaction layers (both directions use OLD h)
  for (int l = 0; l < 3; ++l) {
    k_lin2h<<<ROWS_ALL / 4, 256, 0, stream>>>(
        cur, int_wt_w + (size_t)l * D * D, int_wt_b + l * D,
        int_mt_w + (size_t)l * D * D, int_mt_b + l * D, T1, M2, 1, 0);
    k_msg2v<<<dim3(32, 8, 2), 256, 0, stream>>>(T1, M2, ADJ12, MSG);
    k_gruf<<<ROWS_ALL / 4, 384, 0, stream>>>(MSG, cur, GIHT + (size_t)l * D * 384,
                                             GHHT + (size_t)l * D * 384,
                                             gru_b_ih + l * 384,
                                             gru_b_hh + l * 384, alt);
    float* t = cur; cur = alt; alt = t;
  }

  // pairwise feature precompute (U normal layout, V transposed [b][d][j])
  k_lin2h<<<ROWS_L / 4, 256, 0, stream>>>(cur, A_w1, A_b1, B_w1, B_b1, UA, UB,
                                          1, 0);
  k_lin2h<<<ROWS_T / 4, 256, 0, stream>>>(cur + (size_t)ROWS_L * DC,
                                          A_w1 + D * D, nullptr, B_w1 + D * D,
                                          nullptr, VAT, VBT, N2C, 1);

  // pairwise physics + analytic derivatives
  k_pair<<<dim3(N1C, BB), 256, 0, stream>>>(UA, VAT, UB, VBT, A_w2, A_b2, B_w2,
                                            B_b2, ligand_pos, target_pos, lvdw,
                                            tvdw, lnm, tnm, inter_ind, hb_c,
                                            hp_c, PART);

  // final reduction -> 34 outputs
  k_final<<<1, 256, 0, stream>>>(PART, rotor, rc_c, (float*)d_out);
}